// Round 3
// baseline (1036.077 us; speedup 1.0000x reference)
//
#include <hip/hip_runtime.h>
#include <hip/hip_bf16.h>

typedef __attribute__((ext_vector_type(4))) float floatx4;
typedef __attribute__((ext_vector_type(8))) short short8;

static __device__ __forceinline__ float b2f(short s) {
    unsigned int u = ((unsigned int)(unsigned short)s) << 16;
    float f;
    __builtin_memcpy(&f, &u, 4);
    return f;
}
static __device__ __forceinline__ short f2b(float f) {
    __hip_bfloat16 h = __float2bfloat16(f);
    unsigned short u;
    __builtin_memcpy(&u, &h, 2);
    return (short)u;
}
// Async global->LDS, 16B per lane. LDS dest is wave-uniform base + lane*16 (HW).
static __device__ __forceinline__ void gll16(const void* g, void* l) {
    __builtin_amdgcn_global_load_lds(
        (const __attribute__((address_space(1))) unsigned int*)g,
        (__attribute__((address_space(3))) unsigned int*)l, 16, 0, 0);
}

// Writes flag=1 if buffer at `x` (32-bit words, starting at word `off`) looks like
// packed bf16, 0 if fp32.
__global__ void detect_dtype(const unsigned int* __restrict__ x, int off,
                             int* __restrict__ flag) {
    __shared__ int cnt[256];
    const int tid = threadIdx.x;
    const unsigned int w = x[off + tid];
    const unsigned int e = (w >> 7) & 0xFF;
    cnt[tid] = (e >= 110 && e <= 140) ? 1 : 0;
    __syncthreads();
    for (int s = 128; s > 0; s >>= 1) {
        if (tid < s) cnt[tid] += cnt[tid + s];
        __syncthreads();
    }
    if (tid == 0) *flag = (cnt[0] >= 160) ? 1 : 0;
}

// Convert (fp32 or bf16, per flag) -> packed bf16. n8 = elements/8.
__global__ __launch_bounds__(256) void to_bf16(const void* __restrict__ src,
                                               short* __restrict__ dst,
                                               const int* __restrict__ dflag,
                                               unsigned int n8) {
    const int isb = *dflag;
    const unsigned int i = blockIdx.x * 256 + threadIdx.x;
    if (i >= n8) return;
    const size_t e = (size_t)i * 8;
    if (isb) {
        *(short8*)(dst + e) = *(const short8*)((const short*)src + e);
    } else {
        const float4* sp = (const float4*)((const float*)src + e);
        const float4 f0 = sp[0], f1 = sp[1];
        short8 v;
        v[0] = f2b(f0.x); v[1] = f2b(f0.y); v[2] = f2b(f0.z); v[3] = f2b(f0.w);
        v[4] = f2b(f1.x); v[5] = f2b(f1.y); v[6] = f2b(f1.z); v[7] = f2b(f1.w);
        *(short8*)(dst + e) = v;
    }
}

// ---------------------------------------------------------------------------
// 256x256-tile 8-phase GEMM (C[m,n] = sum_k A[m,k]*B[n,k]); all-bf16 operands.
// (structure unchanged from round 2 — see comments there)
// ---------------------------------------------------------------------------
#define QUAD_MFMA(MH, NH)                                                       \
    _Pragma("unroll") for (int i_ = 0; i_ < 4; ++i_)                            \
    _Pragma("unroll") for (int j_ = 0; j_ < 2; ++j_)                            \
    _Pragma("unroll") for (int kp_ = 0; kp_ < 2; ++kp_)                         \
        acc[(MH)*4 + i_][(NH)*2 + j_] = __builtin_amdgcn_mfma_f32_16x16x32_bf16(\
            aF[i_][kp_], bF[NH][j_][kp_], acc[(MH)*4 + i_][(NH)*2 + j_], 0, 0, 0);

#define READ_A(BUFP, MH)                                                        \
    _Pragma("unroll") for (int i_ = 0; i_ < 4; ++i_) {                          \
        const int r_ = (2 * i_ + wm) * 16 + l16;                                \
        _Pragma("unroll") for (int kp_ = 0; kp_ < 2; ++kp_)                     \
            aF[i_][kp_] = *(const short8*)&(BUFP)[(MH)*8192 + kp_*4096 + r_*32 + swzc]; \
    }

#define READ_B(BUFP, NH)                                                        \
    _Pragma("unroll") for (int j_ = 0; j_ < 2; ++j_) {                          \
        const int r_ = (4 * j_ + wn) * 16 + l16;                                \
        _Pragma("unroll") for (int kp_ = 0; kp_ < 2; ++kp_)                     \
            bF[NH][j_][kp_] = *(const short8*)&(BUFP)[16384 + (NH)*8192 + kp_*4096 + r_*32 + swzc]; \
    }

#define STAGE(BUFP, OPOFF, GBASE, ROW0, TT)                                     \
    {                                                                           \
        const short* g_ = (GBASE) + (size_t)((ROW0) + wave * 16 + (lane >> 2)) * K \
                          + (TT) * 64 + scol;                                   \
        gll16(g_, (BUFP) + (OPOFF) + wave * 512);                               \
        gll16(g_ + 32, (BUFP) + (OPOFF) + 4096 + wave * 512);                   \
    }

__global__ __launch_bounds__(512, 2) void gemm256(const short* __restrict__ A,
                                                  const short* __restrict__ B,
                                                  void* __restrict__ C,
                                                  int M, int N, int K,
                                                  const int* __restrict__ dflag,
                                                  int out_dyn) {
    __shared__ short lds[65536];  // 128 KB
    const int isb = *dflag;
    const int tid = threadIdx.x;
    const int wave = tid >> 6, lane = tid & 63;
    const int wm = wave >> 2, wn = wave & 3;
    const int quad = lane >> 4, l16 = lane & 15;
    const int nwg = gridDim.x * gridDim.y;
    int lin = blockIdx.y * gridDim.x + blockIdx.x;
    lin = (lin & 7) * (nwg >> 3) + (lin >> 3);
    const int m0 = (lin / gridDim.x) * 256, n0 = (lin % gridDim.x) * 256;
    const int swzc = (quad * 8) ^ ((l16 & 8) << 1);
    const int scol = ((lane & 3) * 8) ^ (((lane >> 5) & 1) << 4);
    const int NG = K >> 6;

    floatx4 acc[8][4] = {};
    short8 aF[4][2], bF[2][2][2];

    {
        const int t1p = (1 < NG) ? 1 : NG - 1;
        STAGE(lds, 0, A, m0, 0);
        STAGE(lds, 16384, B, n0, 0);
        STAGE(lds, 16384 + 8192, B, n0 + 128, 0);
        STAGE(lds, 8192, A, m0 + 128, 0);
        STAGE(lds + 32768, 0, A, m0, t1p);
        STAGE(lds + 32768, 16384 + 8192, B, n0 + 128, t1p);
    }
    asm volatile("s_waitcnt vmcnt(4)" ::: "memory");
    __builtin_amdgcn_s_barrier();
    __builtin_amdgcn_sched_barrier(0);

    for (int g = 0; g < NG; ++g) {
        short* bufc = lds + (g & 1) * 32768;
        short* bufn = lds + ((g + 1) & 1) * 32768;
        const int t1 = (g + 1 < NG) ? g + 1 : NG - 1;
        const int t2 = (g + 2 < NG) ? g + 2 : NG - 1;
        READ_A(bufc, 0);
        READ_B(bufc, 0);
        STAGE(bufn, 8192, A, m0 + 128, t1);
        STAGE(bufn, 16384, B, n0, t1);
        __builtin_amdgcn_s_barrier();
        __builtin_amdgcn_s_setprio(1);
        QUAD_MFMA(0, 0);
        __builtin_amdgcn_s_setprio(0);
        __builtin_amdgcn_s_barrier();
        READ_B(bufc, 1);
        __builtin_amdgcn_s_barrier();
        __builtin_amdgcn_s_setprio(1);
        QUAD_MFMA(0, 1);
        __builtin_amdgcn_s_setprio(0);
        __builtin_amdgcn_s_barrier();
        READ_A(bufc, 1);
        STAGE(bufc, 0, A, m0, t2);
        __builtin_amdgcn_s_barrier();
        __builtin_amdgcn_s_setprio(1);
        QUAD_MFMA(1, 1);
        __builtin_amdgcn_s_setprio(0);
        __builtin_amdgcn_s_barrier();
        STAGE(bufc, 16384 + 8192, B, n0 + 128, t2);
        asm volatile("s_waitcnt vmcnt(4)" ::: "memory");
        __builtin_amdgcn_s_barrier();
        __builtin_amdgcn_sched_barrier(0);
        __builtin_amdgcn_s_setprio(1);
        QUAD_MFMA(1, 0);
        __builtin_amdgcn_s_setprio(0);
        __builtin_amdgcn_s_barrier();
    }
    asm volatile("s_waitcnt vmcnt(0)" ::: "memory");

#pragma unroll
    for (int i = 0; i < 8; ++i)
#pragma unroll
        for (int j = 0; j < 4; ++j)
#pragma unroll
            for (int rr = 0; rr < 4; ++rr) {
                const size_t row = m0 + (2 * i + wm) * 16 + quad * 4 + rr;
                const size_t col = n0 + (4 * j + wn) * 16 + l16;
                const float v = acc[i][j][rr];
                if (out_dyn && !isb)
                    ((float*)C)[row * N + col] = v;
                else
                    ((short*)C)[row * N + col] = f2b(v);
            }
}

// Fallback 128x128 GEMM (handles fp32 B via reg-stage) for small-ws final proj.
__global__ __launch_bounds__(256) void gemm_bt_f(const short* __restrict__ A,
                                                 const void* __restrict__ B,
                                                 void* __restrict__ C,
                                                 int M, int N, int K,
                                                 const int* __restrict__ dflag,
                                                 int b_dyn, int out_dyn) {
    __shared__ short As[128 * 32];
    __shared__ short Bs[128 * 32];
    const int isb = *dflag;
    const int b_bf = b_dyn ? isb : 1;
    const int tid = threadIdx.x;
    const int wave = tid >> 6, lane = tid & 63;
    const int quad = lane >> 4, l16 = lane & 15;
    const int wm = (wave >> 1) * 64, wn = (wave & 1) * 64;
    const int m0 = blockIdx.y * 128, n0 = blockIdx.x * 128;
    const int g_r = lane >> 2;
    const int g_c = (lane & 3) * 8;
    const short* agp = A + (size_t)(m0 + wave * 32 + g_r) * K + g_c;
    const short* bgp = (const short*)B + (size_t)(n0 + wave * 32 + g_r) * K + g_c;
    short* const asl0 = &As[(wave * 32) * 32];
    short* const asl1 = &As[(wave * 32 + 16) * 32];
    short* const bsl0 = &Bs[(wave * 32) * 32];
    short* const bsl1 = &Bs[(wave * 32 + 16) * 32];
    const size_t kstep16 = (size_t)16 * K;
    const int s_r = tid >> 1, s_c = (tid & 1) * 16;
    const size_t brow_f = (size_t)(n0 + s_r) * K + s_c;

    floatx4 acc[4][4] = {};
    for (int k0 = 0; k0 < K; k0 += 32) {
        gll16(agp + k0, asl0);
        gll16(agp + k0 + kstep16, asl1);
        if (b_bf) {
            gll16(bgp + k0, bsl0);
            gll16(bgp + k0 + kstep16, bsl1);
        } else {
            const float* bp = (const float*)B + brow_f + k0;
            const float4 f0 = ((const float4*)bp)[0], f1 = ((const float4*)bp)[1];
            const float4 f2 = ((const float4*)bp)[2], f3 = ((const float4*)bp)[3];
            short8 v0, v1;
            v0[0] = f2b(f0.x); v0[1] = f2b(f0.y); v0[2] = f2b(f0.z); v0[3] = f2b(f0.w);
            v0[4] = f2b(f1.x); v0[5] = f2b(f1.y); v0[6] = f2b(f1.z); v0[7] = f2b(f1.w);
            v1[0] = f2b(f2.x); v1[1] = f2b(f2.y); v1[2] = f2b(f2.z); v1[3] = f2b(f2.w);
            v1[4] = f2b(f3.x); v1[5] = f2b(f3.y); v1[6] = f2b(f3.z); v1[7] = f2b(f3.w);
            *(short8*)&Bs[s_r * 32 + s_c] = v0;
            *(short8*)&Bs[s_r * 32 + s_c + 8] = v1;
        }
        __syncthreads();
        short8 af[4], bq[4];
#pragma unroll
        for (int i = 0; i < 4; i++)
            af[i] = *(const short8*)&As[(wm + i * 16 + l16) * 32 + quad * 8];
#pragma unroll
        for (int j = 0; j < 4; j++)
            bq[j] = *(const short8*)&Bs[(wn + j * 16 + l16) * 32 + quad * 8];
#pragma unroll
        for (int i = 0; i < 4; i++)
#pragma unroll
            for (int j = 0; j < 4; j++)
                acc[i][j] = __builtin_amdgcn_mfma_f32_16x16x32_bf16(af[i], bq[j], acc[i][j], 0, 0, 0);
        __syncthreads();
    }
#pragma unroll
    for (int i = 0; i < 4; i++)
#pragma unroll
        for (int j = 0; j < 4; j++)
#pragma unroll
            for (int rr = 0; rr < 4; rr++) {
                const size_t row = m0 + wm + i * 16 + quad * 4 + rr;
                const size_t col = n0 + wn + j * 16 + l16;
                const float v = acc[i][j][rr];
                if (out_dyn && !isb)
                    ((float*)C)[row * N + col] = v;
                else
                    ((short*)C)[row * N + col] = f2b(v);
            }
}

// Transpose V half of KV into Vt[(b*8+kvh)*128 + d][tok] (bf16). Tile 64 tok x 128 d.
__global__ __launch_bounds__(256) void transpose_v(const short* __restrict__ KV,
                                                   short* __restrict__ Vt) {
    __shared__ short Ts[64 * 136];
    const int tid = threadIdx.x;
    const int t0 = blockIdx.x * 64;
    const int kvh = blockIdx.y, b = blockIdx.z;
    const int sr = tid >> 2, sc = (tid & 3) * 32;
    const short* src = KV + (size_t)(b * 1024 + t0 + sr) * 2048 + 1024 + kvh * 128 + sc;
#pragma unroll
    for (int j = 0; j < 4; ++j)
        *(short8*)&Ts[sr * 136 + sc + 8 * j] = *(const short8*)(src + 8 * j);
    __syncthreads();
    short* dst = Vt + (size_t)(b * 8 + kvh) * 128 * 1024 + t0;
#pragma unroll
    for (int p = 0; p < 4; ++p) {
        const int d = p * 32 + (tid >> 3);
        const int tk = (tid & 7) * 8;
        short8 v;
#pragma unroll
        for (int e = 0; e < 8; ++e) v[e] = Ts[(tk + e) * 136 + d];
        *(short8*)(dst + (size_t)d * 1024 + tk) = v;
    }
}

// Precompute cos/sin LUT (65536 entries) from freqs [1024][64].
__global__ __launch_bounds__(256) void rope_lut(const void* __restrict__ freqs,
                                                const int* __restrict__ fflag,
                                                float2* __restrict__ cs) {
    const int isb = *fflag;
    const int i = blockIdx.x * 256 + threadIdx.x;
    const float f = isb ? b2f(((const short*)freqs)[i]) : ((const float*)freqs)[i];
    float sv, cv;
    __sincosf(f, &sv, &cv);
    cs[i] = make_float2(cv, sv);
}

// Vectorized RoPE: each thread rotates 4 pairs (one short8). Q additionally
// pre-scaled by 1/sqrt(d) (folded out of attention).
__global__ __launch_bounds__(256) void rope_kernel(short* __restrict__ Qb,
                                                   short* __restrict__ Kb,
                                                   const float2* __restrict__ cs) {
    const int g = blockIdx.x * 256 + threadIdx.x;
    constexpr int QG = 4096 * 512;   // Q groups: 4096 tok x 32 h x (64/4)
    short* base;
    int t, gp;
    float qs;
    if (g < QG) {
        t = g >> 9;
        const int rem = g & 511;
        gp = rem & 15;
        base = Qb + (size_t)t * 4096 + (rem >> 4) * 128 + gp * 8;
        qs = 0.08838834764831845f;
    } else {
        const int i = g - QG;
        t = i >> 7;
        const int rem = i & 127;
        gp = rem & 15;
        base = Kb + (size_t)t * 2048 + (rem >> 4) * 128 + gp * 8;
        qs = 1.0f;
    }
    const int fi0 = (t & 1023) * 64 + gp * 4;
    short8 v = *(const short8*)base;
    short8 r;
#pragma unroll
    for (int j = 0; j < 4; ++j) {
        const float2 c = cs[fi0 + j];
        const float a = b2f(v[2 * j]);
        const float bb = b2f(v[2 * j + 1]);
        r[2 * j]     = f2b((a * c.x - bb * c.y) * qs);
        r[2 * j + 1] = f2b((a * c.y + bb * c.x) * qs);
    }
    *(short8*)base = r;
}

// Flash attention v2: no K/V/Q LDS staging (K,V^T are L2-resident, fragments
// loaded directly from global as 16B vectors), Q hoisted, scale pre-folded,
// Ps is per-wave-private (rows wave*16..+15) -> zero __syncthreads.
__global__ __launch_bounds__(256) void attn_kernel(const short* __restrict__ Q,
                                                   const short* __restrict__ Kc,
                                                   const short* __restrict__ Vt,
                                                   short* __restrict__ AO) {
    constexpr int LP = 72;
    __shared__ short Ps[64 * LP];
    const int tid = threadIdx.x;
    const int qt = gridDim.x - 1 - blockIdx.x;   // long tiles dispatch first
    const int h = blockIdx.y, b = blockIdx.z;
    const int kvh = h >> 2;
    const size_t tbase = (size_t)b * 1024;
    const int q0 = qt * 64;
    const int wave = tid >> 6, lane = tid & 63;
    const int quad = lane >> 4, l16 = lane & 15;
    // Q fragments: hoisted, direct from global (rope already applied 1/sqrt(d))
    short8 aq[4];
    {
        const short* qp = Q + (tbase + q0 + wave * 16 + l16) * 4096 + h * 128 + quad * 8;
#pragma unroll
        for (int kk = 0; kk < 4; ++kk) aq[kk] = *(const short8*)(qp + kk * 32);
    }
    const short* kb = Kc + tbase * 2048 + (size_t)kvh * 128 + quad * 8;
    const short* vb = Vt + ((size_t)(b * 8 + kvh) * 128 + l16) * 1024 + quad * 8;
    floatx4 o[8] = {};
    float mrow[4], lrow[4];
#pragma unroll
    for (int rr = 0; rr < 4; rr++) { mrow[rr] = -1.0e30f; lrow[rr] = 0.0f; }
    for (int kt = 0; kt <= qt; kt++) {
        // ---- QK^T: K fragments direct from global (L2)
        floatx4 s[4];
#pragma unroll
        for (int j = 0; j < 4; j++) {
            floatx4 acc = {};
#pragma unroll
            for (int kk = 0; kk < 4; kk++) {
                const short8 bk = *(const short8*)(kb +
                    (size_t)(kt * 64 + j * 16 + l16) * 2048 + kk * 32);
                acc = __builtin_amdgcn_mfma_f32_16x16x32_bf16(aq[kk], bk, acc, 0, 0, 0);
            }
            s[j] = acc;
        }
        const int qrow = q0 + wave * 16 + quad * 4;
#pragma unroll
        for (int j = 0; j < 4; j++)
#pragma unroll
            for (int rr = 0; rr < 4; rr++) {
                const int key = kt * 64 + j * 16 + l16;
                s[j][rr] = (key > qrow + rr) ? -1.0e9f : s[j][rr];
            }
        // ---- online softmax (16-lane spans; rows split by quad)
        float alpha[4];
#pragma unroll
        for (int rr = 0; rr < 4; rr++) {
            float mx = fmaxf(fmaxf(s[0][rr], s[1][rr]), fmaxf(s[2][rr], s[3][rr]));
#pragma unroll
            for (int off = 1; off < 16; off <<= 1)
                mx = fmaxf(mx, __shfl_xor(mx, off, 64));
            const float mnew = fmaxf(mrow[rr], mx);
            alpha[rr] = __expf(mrow[rr] - mnew);
            float rsum = 0.0f;
#pragma unroll
            for (int j = 0; j < 4; j++) {
                const float p = __expf(s[j][rr] - mnew);
                s[j][rr] = p;
                rsum += p;
            }
#pragma unroll
            for (int off = 1; off < 16; off <<= 1)
                rsum += __shfl_xor(rsum, off, 64);
            lrow[rr] = lrow[rr] * alpha[rr] + rsum;
            mrow[rr] = mnew;
        }
#pragma unroll
        for (int c = 0; c < 8; c++)
#pragma unroll
            for (int rr = 0; rr < 4; rr++)
                o[c][rr] *= alpha[rr];
        // ---- P roundtrip through per-wave-private LDS rows (no block barrier)
        asm volatile("s_waitcnt lgkmcnt(0)" ::: "memory");   // WAR vs prev ap reads
        __builtin_amdgcn_sched_barrier(0);
#pragma unroll
        for (int j = 0; j < 4; j++)
#pragma unroll
            for (int rr = 0; rr < 4; rr++)
                Ps[(wave * 16 + quad * 4 + rr) * LP + j * 16 + l16] = f2b(s[j][rr]);
        asm volatile("s_waitcnt lgkmcnt(0)" ::: "memory");   // RAW: writes visible
        __builtin_amdgcn_sched_barrier(0);
        short8 ap[2];
        ap[0] = *(const short8*)&Ps[(wave * 16 + l16) * LP + quad * 8];
        ap[1] = *(const short8*)&Ps[(wave * 16 + l16) * LP + 32 + quad * 8];
        // ---- PV: V^T fragments direct from global (L2)
#pragma unroll
        for (int c = 0; c < 8; c++) {
#pragma unroll
            for (int kk = 0; kk < 2; kk++) {
                const short8 bv = *(const short8*)(vb +
                    (size_t)(c * 16) * 1024 + kt * 64 + kk * 32);
                o[c] = __builtin_amdgcn_mfma_f32_16x16x32_bf16(ap[kk], bv, o[c], 0, 0, 0);
            }
        }
    }
    float invl[4];
#pragma unroll
    for (int rr = 0; rr < 4; rr++) invl[rr] = 1.0f / lrow[rr];
#pragma unroll
    for (int c = 0; c < 8; c++)
#pragma unroll
        for (int rr = 0; rr < 4; rr++) {
            const size_t row = tbase + q0 + wave * 16 + quad * 4 + rr;
            AO[row * 4096 + h * 128 + c * 16 + l16] = f2b(o[c][rr] * invl[rr]);
        }
}

extern "C" void kernel_launch(void* const* d_in, const int* in_sizes, int n_in,
                              void* d_out, int out_size, void* d_ws, size_t ws_size,
                              hipStream_t stream) {
    // inputs: x, wq, wk, wv, wo, freqs, mask(unused), starting_pos(unused)
    const void* x     = d_in[0];
    const void* wq    = d_in[1];
    const void* wk    = d_in[2];
    const void* wv    = d_in[3];
    const void* wo    = d_in[4];
    const void* freqs = d_in[5];
    char* ws = (char*)d_ws;
    int* flag = (int*)ws;                        // flag[0]: x/weights, flag[1]: freqs
    short* KV = (short*)(ws + 256);              // fused K|V cache: [4096][2048] bf16 = 16 MB
    short* WB = (short*)(ws + 256 + 16777216);   // weight bf16 scratch 32 MB; becomes AO
    short* AO = WB;                              // attn out [4096][4096] bf16
    short* WOB = (short*)(ws + 256 + 16777216 + 33554432);  // wo bf16 (only if ws allows)
    short* Qb = (short*)d_out;                   // Q bf16, d_out lower half [0,32MB)
    short* Xb = (short*)d_out + 16777216;        // x bf16, d_out upper half (dead after KV gemm)
    short* Vtb = (short*)d_out + 16777216;       // V^T [4096 dh][1024 tok] = 8 MB (reuses Xb)
    float2* cs = (float2*)((char*)d_out + 33554432 + 8388608);  // rope LUT 512 KB (after Vt)
    const bool big_ws = ws_size >= (size_t)(256 + 16777216 + 33554432 + 33554432);

    detect_dtype<<<1, 256, 0, stream>>>((const unsigned int*)x, 0, flag);
    detect_dtype<<<1, 256, 0, stream>>>((const unsigned int*)freqs, 100, flag + 1);
    to_bf16<<<8192, 256, 0, stream>>>(x, Xb, flag, 2097152);
    to_bf16<<<8192, 256, 0, stream>>>(wq, WB, flag, 2097152);
    gemm256<<<dim3(16, 16), 512, 0, stream>>>(Xb, WB, Qb, 4096, 4096, 4096, flag, 0);
    to_bf16<<<2048, 256, 0, stream>>>(wk, WB, flag, 524288);
    to_bf16<<<2048, 256, 0, stream>>>(wv, WB + 4194304, flag, 524288);
    gemm256<<<dim3(8, 16), 512, 0, stream>>>(Xb, WB, KV, 4096, 2048, 4096, flag, 0);
    // Xb dead from here: its region becomes V^T + rope LUT
    transpose_v<<<dim3(16, 8, 4), 256, 0, stream>>>(KV, Vtb);
    rope_lut<<<256, 256, 0, stream>>>(freqs, flag + 1, cs);
    rope_kernel<<<10240, 256, 0, stream>>>(Qb, KV, cs);
    attn_kernel<<<dim3(16, 32, 4), 256, 0, stream>>>(Qb, KV, Vtb, AO);
    if (big_ws) {
        to_bf16<<<8192, 256, 0, stream>>>(wo, WOB, flag, 2097152);
        gemm256<<<dim3(16, 16), 512, 0, stream>>>(AO, WOB, d_out, 4096, 4096, 4096, flag, 1);
    } else {
        gemm_bt_f<<<dim3(32, 32), 256, 0, stream>>>(AO, wo, d_out, 4096, 4096, 4096, flag, 1, 1);
    }
}

// Round 4
// 726.957 us; speedup vs baseline: 1.4252x; 1.4252x over previous
//
#include <hip/hip_runtime.h>
#include <hip/hip_bf16.h>

typedef __attribute__((ext_vector_type(4))) float floatx4;
typedef __attribute__((ext_vector_type(8))) short short8;

static __device__ __forceinline__ float b2f(short s) {
    unsigned int u = ((unsigned int)(unsigned short)s) << 16;
    float f;
    __builtin_memcpy(&f, &u, 4);
    return f;
}
static __device__ __forceinline__ short f2b(float f) {
    __hip_bfloat16 h = __float2bfloat16(f);
    unsigned short u;
    __builtin_memcpy(&u, &h, 2);
    return (short)u;
}
// Async global->LDS, 16B per lane. LDS dest is wave-uniform base + lane*16 (HW).
static __device__ __forceinline__ void gll16(const void* g, void* l) {
    __builtin_amdgcn_global_load_lds(
        (const __attribute__((address_space(1))) unsigned int*)g,
        (__attribute__((address_space(3))) unsigned int*)l, 16, 0, 0);
}

// Writes flag=1 if buffer at `x` (32-bit words, starting at word `off`) looks like
// packed bf16, 0 if fp32.
__global__ void detect_dtype(const unsigned int* __restrict__ x, int off,
                             int* __restrict__ flag) {
    __shared__ int cnt[256];
    const int tid = threadIdx.x;
    const unsigned int w = x[off + tid];
    const unsigned int e = (w >> 7) & 0xFF;
    cnt[tid] = (e >= 110 && e <= 140) ? 1 : 0;
    __syncthreads();
    for (int s = 128; s > 0; s >>= 1) {
        if (tid < s) cnt[tid] += cnt[tid + s];
        __syncthreads();
    }
    if (tid == 0) *flag = (cnt[0] >= 160) ? 1 : 0;
}

// Convert (fp32 or bf16, per flag) -> packed bf16. n8 = elements/8.
__global__ __launch_bounds__(256) void to_bf16(const void* __restrict__ src,
                                               short* __restrict__ dst,
                                               const int* __restrict__ dflag,
                                               unsigned int n8) {
    const int isb = *dflag;
    const unsigned int i = blockIdx.x * 256 + threadIdx.x;
    if (i >= n8) return;
    const size_t e = (size_t)i * 8;
    if (isb) {
        *(short8*)(dst + e) = *(const short8*)((const short*)src + e);
    } else {
        const float4* sp = (const float4*)((const float*)src + e);
        const float4 f0 = sp[0], f1 = sp[1];
        short8 v;
        v[0] = f2b(f0.x); v[1] = f2b(f0.y); v[2] = f2b(f0.z); v[3] = f2b(f0.w);
        v[4] = f2b(f1.x); v[5] = f2b(f1.y); v[6] = f2b(f1.z); v[7] = f2b(f1.w);
        *(short8*)(dst + e) = v;
    }
}

// ---------------------------------------------------------------------------
// 256x256-tile 8-phase GEMM (C[m,n] = sum_k A[m,k]*B[n,k]); all-bf16 operands.
// (structure unchanged from round 2 — see comments there)
// ---------------------------------------------------------------------------
#define QUAD_MFMA(MH, NH)                                                       \
    _Pragma("unroll") for (int i_ = 0; i_ < 4; ++i_)                            \
    _Pragma("unroll") for (int j_ = 0; j_ < 2; ++j_)                            \
    _Pragma("unroll") for (int kp_ = 0; kp_ < 2; ++kp_)                         \
        acc[(MH)*4 + i_][(NH)*2 + j_] = __builtin_amdgcn_mfma_f32_16x16x32_bf16(\
            aF[i_][kp_], bF[NH][j_][kp_], acc[(MH)*4 + i_][(NH)*2 + j_], 0, 0, 0);

#define READ_A(BUFP, MH)                                                        \
    _Pragma("unroll") for (int i_ = 0; i_ < 4; ++i_) {                          \
        const int r_ = (2 * i_ + wm) * 16 + l16;                                \
        _Pragma("unroll") for (int kp_ = 0; kp_ < 2; ++kp_)                     \
            aF[i_][kp_] = *(const short8*)&(BUFP)[(MH)*8192 + kp_*4096 + r_*32 + swzc]; \
    }

#define READ_B(BUFP, NH)                                                        \
    _Pragma("unroll") for (int j_ = 0; j_ < 2; ++j_) {                          \
        const int r_ = (4 * j_ + wn) * 16 + l16;                                \
        _Pragma("unroll") for (int kp_ = 0; kp_ < 2; ++kp_)                     \
            bF[NH][j_][kp_] = *(const short8*)&(BUFP)[16384 + (NH)*8192 + kp_*4096 + r_*32 + swzc]; \
    }

#define STAGE(BUFP, OPOFF, GBASE, ROW0, TT)                                     \
    {                                                                           \
        const short* g_ = (GBASE) + (size_t)((ROW0) + wave * 16 + (lane >> 2)) * K \
                          + (TT) * 64 + scol;                                   \
        gll16(g_, (BUFP) + (OPOFF) + wave * 512);                               \
        gll16(g_ + 32, (BUFP) + (OPOFF) + 4096 + wave * 512);                   \
    }

__global__ __launch_bounds__(512, 2) void gemm256(const short* __restrict__ A,
                                                  const short* __restrict__ B,
                                                  void* __restrict__ C,
                                                  int M, int N, int K,
                                                  const int* __restrict__ dflag,
                                                  int out_dyn) {
    __shared__ short lds[65536];  // 128 KB
    const int isb = *dflag;
    const int tid = threadIdx.x;
    const int wave = tid >> 6, lane = tid & 63;
    const int wm = wave >> 2, wn = wave & 3;
    const int quad = lane >> 4, l16 = lane & 15;
    const int nwg = gridDim.x * gridDim.y;
    int lin = blockIdx.y * gridDim.x + blockIdx.x;
    lin = (lin & 7) * (nwg >> 3) + (lin >> 3);
    const int m0 = (lin / gridDim.x) * 256, n0 = (lin % gridDim.x) * 256;
    const int swzc = (quad * 8) ^ ((l16 & 8) << 1);
    const int scol = ((lane & 3) * 8) ^ (((lane >> 5) & 1) << 4);
    const int NG = K >> 6;

    floatx4 acc[8][4] = {};
    short8 aF[4][2], bF[2][2][2];

    {
        const int t1p = (1 < NG) ? 1 : NG - 1;
        STAGE(lds, 0, A, m0, 0);
        STAGE(lds, 16384, B, n0, 0);
        STAGE(lds, 16384 + 8192, B, n0 + 128, 0);
        STAGE(lds, 8192, A, m0 + 128, 0);
        STAGE(lds + 32768, 0, A, m0, t1p);
        STAGE(lds + 32768, 16384 + 8192, B, n0 + 128, t1p);
    }
    asm volatile("s_waitcnt vmcnt(4)" ::: "memory");
    __builtin_amdgcn_s_barrier();
    __builtin_amdgcn_sched_barrier(0);

    for (int g = 0; g < NG; ++g) {
        short* bufc = lds + (g & 1) * 32768;
        short* bufn = lds + ((g + 1) & 1) * 32768;
        const int t1 = (g + 1 < NG) ? g + 1 : NG - 1;
        const int t2 = (g + 2 < NG) ? g + 2 : NG - 1;
        READ_A(bufc, 0);
        READ_B(bufc, 0);
        STAGE(bufn, 8192, A, m0 + 128, t1);
        STAGE(bufn, 16384, B, n0, t1);
        __builtin_amdgcn_s_barrier();
        __builtin_amdgcn_s_setprio(1);
        QUAD_MFMA(0, 0);
        __builtin_amdgcn_s_setprio(0);
        __builtin_amdgcn_s_barrier();
        READ_B(bufc, 1);
        __builtin_amdgcn_s_barrier();
        __builtin_amdgcn_s_setprio(1);
        QUAD_MFMA(0, 1);
        __builtin_amdgcn_s_setprio(0);
        __builtin_amdgcn_s_barrier();
        READ_A(bufc, 1);
        STAGE(bufc, 0, A, m0, t2);
        __builtin_amdgcn_s_barrier();
        __builtin_amdgcn_s_setprio(1);
        QUAD_MFMA(1, 1);
        __builtin_amdgcn_s_setprio(0);
        __builtin_amdgcn_s_barrier();
        STAGE(bufc, 16384 + 8192, B, n0 + 128, t2);
        asm volatile("s_waitcnt vmcnt(4)" ::: "memory");
        __builtin_amdgcn_s_barrier();
        __builtin_amdgcn_sched_barrier(0);
        __builtin_amdgcn_s_setprio(1);
        QUAD_MFMA(1, 0);
        __builtin_amdgcn_s_setprio(0);
        __builtin_amdgcn_s_barrier();
    }
    asm volatile("s_waitcnt vmcnt(0)" ::: "memory");

#pragma unroll
    for (int i = 0; i < 8; ++i)
#pragma unroll
        for (int j = 0; j < 4; ++j)
#pragma unroll
            for (int rr = 0; rr < 4; ++rr) {
                const size_t row = m0 + (2 * i + wm) * 16 + quad * 4 + rr;
                const size_t col = n0 + (4 * j + wn) * 16 + l16;
                const float v = acc[i][j][rr];
                if (out_dyn && !isb)
                    ((float*)C)[row * N + col] = v;
                else
                    ((short*)C)[row * N + col] = f2b(v);
            }
}

// Fallback 128x128 GEMM (handles fp32 B via reg-stage) for small-ws final proj.
__global__ __launch_bounds__(256) void gemm_bt_f(const short* __restrict__ A,
                                                 const void* __restrict__ B,
                                                 void* __restrict__ C,
                                                 int M, int N, int K,
                                                 const int* __restrict__ dflag,
                                                 int b_dyn, int out_dyn) {
    __shared__ short As[128 * 32];
    __shared__ short Bs[128 * 32];
    const int isb = *dflag;
    const int b_bf = b_dyn ? isb : 1;
    const int tid = threadIdx.x;
    const int wave = tid >> 6, lane = tid & 63;
    const int quad = lane >> 4, l16 = lane & 15;
    const int wm = (wave >> 1) * 64, wn = (wave & 1) * 64;
    const int m0 = blockIdx.y * 128, n0 = blockIdx.x * 128;
    const int g_r = lane >> 2;
    const int g_c = (lane & 3) * 8;
    const short* agp = A + (size_t)(m0 + wave * 32 + g_r) * K + g_c;
    const short* bgp = (const short*)B + (size_t)(n0 + wave * 32 + g_r) * K + g_c;
    short* const asl0 = &As[(wave * 32) * 32];
    short* const asl1 = &As[(wave * 32 + 16) * 32];
    short* const bsl0 = &Bs[(wave * 32) * 32];
    short* const bsl1 = &Bs[(wave * 32 + 16) * 32];
    const size_t kstep16 = (size_t)16 * K;
    const int s_r = tid >> 1, s_c = (tid & 1) * 16;
    const size_t brow_f = (size_t)(n0 + s_r) * K + s_c;

    floatx4 acc[4][4] = {};
    for (int k0 = 0; k0 < K; k0 += 32) {
        gll16(agp + k0, asl0);
        gll16(agp + k0 + kstep16, asl1);
        if (b_bf) {
            gll16(bgp + k0, bsl0);
            gll16(bgp + k0 + kstep16, bsl1);
        } else {
            const float* bp = (const float*)B + brow_f + k0;
            const float4 f0 = ((const float4*)bp)[0], f1 = ((const float4*)bp)[1];
            const float4 f2 = ((const float4*)bp)[2], f3 = ((const float4*)bp)[3];
            short8 v0, v1;
            v0[0] = f2b(f0.x); v0[1] = f2b(f0.y); v0[2] = f2b(f0.z); v0[3] = f2b(f0.w);
            v0[4] = f2b(f1.x); v0[5] = f2b(f1.y); v0[6] = f2b(f1.z); v0[7] = f2b(f1.w);
            v1[0] = f2b(f2.x); v1[1] = f2b(f2.y); v1[2] = f2b(f2.z); v1[3] = f2b(f2.w);
            v1[4] = f2b(f3.x); v1[5] = f2b(f3.y); v1[6] = f2b(f3.z); v1[7] = f2b(f3.w);
            *(short8*)&Bs[s_r * 32 + s_c] = v0;
            *(short8*)&Bs[s_r * 32 + s_c + 8] = v1;
        }
        __syncthreads();
        short8 af[4], bq[4];
#pragma unroll
        for (int i = 0; i < 4; i++)
            af[i] = *(const short8*)&As[(wm + i * 16 + l16) * 32 + quad * 8];
#pragma unroll
        for (int j = 0; j < 4; j++)
            bq[j] = *(const short8*)&Bs[(wn + j * 16 + l16) * 32 + quad * 8];
#pragma unroll
        for (int i = 0; i < 4; i++)
#pragma unroll
            for (int j = 0; j < 4; j++)
                acc[i][j] = __builtin_amdgcn_mfma_f32_16x16x32_bf16(af[i], bq[j], acc[i][j], 0, 0, 0);
        __syncthreads();
    }
#pragma unroll
    for (int i = 0; i < 4; i++)
#pragma unroll
        for (int j = 0; j < 4; j++)
#pragma unroll
            for (int rr = 0; rr < 4; rr++) {
                const size_t row = m0 + wm + i * 16 + quad * 4 + rr;
                const size_t col = n0 + wn + j * 16 + l16;
                const float v = acc[i][j][rr];
                if (out_dyn && !isb)
                    ((float*)C)[row * N + col] = v;
                else
                    ((short*)C)[row * N + col] = f2b(v);
            }
}

// Transpose V half of KV into Vt[(b*8+kvh)*128 + d][tok] (bf16). Tile 64 tok x 128 d.
__global__ __launch_bounds__(256) void transpose_v(const short* __restrict__ KV,
                                                   short* __restrict__ Vt) {
    __shared__ short Ts[64 * 136];
    const int tid = threadIdx.x;
    const int t0 = blockIdx.x * 64;
    const int kvh = blockIdx.y, b = blockIdx.z;
    const int sr = tid >> 2, sc = (tid & 3) * 32;
    const short* src = KV + (size_t)(b * 1024 + t0 + sr) * 2048 + 1024 + kvh * 128 + sc;
#pragma unroll
    for (int j = 0; j < 4; ++j)
        *(short8*)&Ts[sr * 136 + sc + 8 * j] = *(const short8*)(src + 8 * j);
    __syncthreads();
    short* dst = Vt + (size_t)(b * 8 + kvh) * 128 * 1024 + t0;
#pragma unroll
    for (int p = 0; p < 4; ++p) {
        const int d = p * 32 + (tid >> 3);
        const int tk = (tid & 7) * 8;
        short8 v;
#pragma unroll
        for (int e = 0; e < 8; ++e) v[e] = Ts[(tk + e) * 136 + d];
        *(short8*)(dst + (size_t)d * 1024 + tk) = v;
    }
}

// Precompute cos/sin LUT (65536 entries) from freqs [1024][64].
__global__ __launch_bounds__(256) void rope_lut(const void* __restrict__ freqs,
                                                const int* __restrict__ fflag,
                                                float2* __restrict__ cs) {
    const int isb = *fflag;
    const int i = blockIdx.x * 256 + threadIdx.x;
    const float f = isb ? b2f(((const short*)freqs)[i]) : ((const float*)freqs)[i];
    float sv, cv;
    __sincosf(f, &sv, &cv);
    cs[i] = make_float2(cv, sv);
}

// Vectorized RoPE: each thread rotates 4 pairs (one short8). Q additionally
// pre-scaled by 1/sqrt(d) (folded out of attention).
__global__ __launch_bounds__(256) void rope_kernel(short* __restrict__ Qb,
                                                   short* __restrict__ Kb,
                                                   const float2* __restrict__ cs) {
    const int g = blockIdx.x * 256 + threadIdx.x;
    constexpr int QG = 4096 * 512;   // Q groups: 4096 tok x 32 h x (64/4)
    short* base;
    int t, gp;
    float qs;
    if (g < QG) {
        t = g >> 9;
        const int rem = g & 511;
        gp = rem & 15;
        base = Qb + (size_t)t * 4096 + (rem >> 4) * 128 + gp * 8;
        qs = 0.08838834764831845f;
    } else {
        const int i = g - QG;
        t = i >> 7;
        const int rem = i & 127;
        gp = rem & 15;
        base = Kb + (size_t)t * 2048 + (rem >> 4) * 128 + gp * 8;
        qs = 1.0f;
    }
    const int fi0 = (t & 1023) * 64 + gp * 4;
    short8 v = *(const short8*)base;
    short8 r;
#pragma unroll
    for (int j = 0; j < 4; ++j) {
        const float2 c = cs[fi0 + j];
        const float a = b2f(v[2 * j]);
        const float bb = b2f(v[2 * j + 1]);
        r[2 * j]     = f2b((a * c.x - bb * c.y) * qs);
        r[2 * j + 1] = f2b((a * c.y + bb * c.x) * qs);
    }
    *(short8*)base = r;
}

// Flash attention v4: cooperative async gll staging of K and pre-transposed V^T
// into XOR-swizzled LDS tiles; Q hoisted in regs; scale pre-folded; per-wave Ps.
// Counted-vmcnt split: QK^T runs while V^T staging is still in flight.
__global__ __launch_bounds__(256) void attn_kernel(const short* __restrict__ Q,
                                                   const short* __restrict__ Kc,
                                                   const short* __restrict__ Vt,
                                                   short* __restrict__ AO) {
    constexpr int LP = 72;
    __shared__ short Ks[64 * 128];    // K tile, rows swizzled: col ^= (row&7)<<3
    __shared__ short Vts[128 * 64];   // V^T tile [d][tok], same swizzle
    __shared__ short Ps[64 * LP];
    const int tid = threadIdx.x;
    const int qt = gridDim.x - 1 - blockIdx.x;   // long tiles dispatch first
    const int h = blockIdx.y, b = blockIdx.z;
    const int kvh = h >> 2;
    const size_t tbase = (size_t)b * 1024;
    const int q0 = qt * 64;
    const int wave = tid >> 6, lane = tid & 63;
    const int quad = lane >> 4, l16 = lane & 15;
    // hoisted Q fragments (rope already folded 1/sqrt(d))
    short8 aq[4];
    {
        const short* qp = Q + (tbase + q0 + wave * 16 + l16) * 4096 + h * 128 + quad * 8;
#pragma unroll
        for (int kk = 0; kk < 4; ++kk) aq[kk] = *(const short8*)(qp + kk * 32);
    }
    // staging lane coords (K: 4 rows/gll x 16 slots; V: 8 rows/gll x 8 slots)
    const int krl = lane >> 4, kc = (lane & 15) * 8;
    const int vrl = lane >> 3, vc = (lane & 7) * 8;
    const short* kbase0 = Kc + tbase * 2048 + kvh * 128;
    const short* vbase0 = Vt + (size_t)(b * 8 + kvh) * 128 * 1024;
    const int swz = (l16 & 7) << 3;   // read-side XOR (shorts)
    floatx4 o[8] = {};
    float mrow[4], lrow[4];
#pragma unroll
    for (int rr = 0; rr < 4; rr++) { mrow[rr] = -1.0e30f; lrow[rr] = 0.0f; }
    for (int kt = 0; kt <= qt; kt++) {
        if (kt > 0) __syncthreads();   // WAR: all waves done with Ks/Vts
        // ---- issue K staging (4 gll/wave), then V^T staging (4 gll/wave)
        const short* kbase = kbase0 + (size_t)kt * 64 * 2048;
#pragma unroll
        for (int g = 0; g < 4; ++g) {
            const int r = wave * 16 + g * 4 + krl;
            gll16(kbase + (size_t)r * 2048 + (kc ^ ((r & 7) << 3)),
                  Ks + (wave * 16 + g * 4) * 128);
        }
#pragma unroll
        for (int g = 0; g < 4; ++g) {
            const int r = wave * 32 + g * 8 + vrl;
            gll16(vbase0 + (size_t)r * 1024 + kt * 64 + (vc ^ ((r & 7) << 3)),
                  Vts + (wave * 32 + g * 8) * 64);
        }
        asm volatile("s_waitcnt vmcnt(4)" ::: "memory");  // K tile landed; V in flight
        __builtin_amdgcn_s_barrier();
        __builtin_amdgcn_sched_barrier(0);
        // ---- QK^T from swizzled LDS
        floatx4 s[4];
#pragma unroll
        for (int j = 0; j < 4; j++) {
            floatx4 acc = {};
#pragma unroll
            for (int kk = 0; kk < 4; kk++) {
                const short8 bk = *(const short8*)&Ks[(j * 16 + l16) * 128 +
                                                     ((kk * 32 + quad * 8) ^ swz)];
                acc = __builtin_amdgcn_mfma_f32_16x16x32_bf16(aq[kk], bk, acc, 0, 0, 0);
            }
            s[j] = acc;
        }
        const int qrow = q0 + wave * 16 + quad * 4;
#pragma unroll
        for (int j = 0; j < 4; j++)
#pragma unroll
            for (int rr = 0; rr < 4; rr++) {
                const int key = kt * 64 + j * 16 + l16;
                s[j][rr] = (key > qrow + rr) ? -1.0e9f : s[j][rr];
            }
        // ---- online softmax (16-lane spans; rows split by quad)
        float alpha[4];
#pragma unroll
        for (int rr = 0; rr < 4; rr++) {
            float mx = fmaxf(fmaxf(s[0][rr], s[1][rr]), fmaxf(s[2][rr], s[3][rr]));
#pragma unroll
            for (int off = 1; off < 16; off <<= 1)
                mx = fmaxf(mx, __shfl_xor(mx, off, 64));
            const float mnew = fmaxf(mrow[rr], mx);
            alpha[rr] = __expf(mrow[rr] - mnew);
            float rsum = 0.0f;
#pragma unroll
            for (int j = 0; j < 4; j++) {
                const float p = __expf(s[j][rr] - mnew);
                s[j][rr] = p;
                rsum += p;
            }
#pragma unroll
            for (int off = 1; off < 16; off <<= 1)
                rsum += __shfl_xor(rsum, off, 64);
            lrow[rr] = lrow[rr] * alpha[rr] + rsum;
            mrow[rr] = mnew;
        }
#pragma unroll
        for (int c = 0; c < 8; c++)
#pragma unroll
            for (int rr = 0; rr < 4; rr++)
                o[c][rr] *= alpha[rr];
        // ---- P roundtrip through per-wave-private LDS rows
#pragma unroll
        for (int j = 0; j < 4; j++)
#pragma unroll
            for (int rr = 0; rr < 4; rr++)
                Ps[(wave * 16 + quad * 4 + rr) * LP + j * 16 + l16] = f2b(s[j][rr]);
        asm volatile("s_waitcnt lgkmcnt(0)" ::: "memory");   // RAW: writes visible
        __builtin_amdgcn_sched_barrier(0);
        short8 ap[2];
        ap[0] = *(const short8*)&Ps[(wave * 16 + l16) * LP + quad * 8];
        ap[1] = *(const short8*)&Ps[(wave * 16 + l16) * LP + 32 + quad * 8];
        // ---- wait V^T staging (was in flight under QK^T+softmax), then PV
        asm volatile("s_waitcnt vmcnt(0)" ::: "memory");
        __builtin_amdgcn_s_barrier();
        __builtin_amdgcn_sched_barrier(0);
#pragma unroll
        for (int c = 0; c < 8; c++) {
#pragma unroll
            for (int kk = 0; kk < 2; kk++) {
                const short8 bv = *(const short8*)&Vts[(c * 16 + l16) * 64 +
                                                      ((kk * 32 + quad * 8) ^ swz)];
                o[c] = __builtin_amdgcn_mfma_f32_16x16x32_bf16(ap[kk], bv, o[c], 0, 0, 0);
            }
        }
    }
    float invl[4];
#pragma unroll
    for (int rr = 0; rr < 4; rr++) invl[rr] = 1.0f / lrow[rr];
#pragma unroll
    for (int c = 0; c < 8; c++)
#pragma unroll
        for (int rr = 0; rr < 4; rr++) {
            const size_t row = tbase + q0 + wave * 16 + quad * 4 + rr;
            AO[row * 4096 + h * 128 + c * 16 + l16] = f2b(o[c][rr] * invl[rr]);
        }
}

extern "C" void kernel_launch(void* const* d_in, const int* in_sizes, int n_in,
                              void* d_out, int out_size, void* d_ws, size_t ws_size,
                              hipStream_t stream) {
    // inputs: x, wq, wk, wv, wo, freqs, mask(unused), starting_pos(unused)
    const void* x     = d_in[0];
    const void* wq    = d_in[1];
    const void* wk    = d_in[2];
    const void* wv    = d_in[3];
    const void* wo    = d_in[4];
    const void* freqs = d_in[5];
    char* ws = (char*)d_ws;
    int* flag = (int*)ws;                        // flag[0]: x/weights, flag[1]: freqs
    short* KV = (short*)(ws + 256);              // fused K|V cache: [4096][2048] bf16 = 16 MB
    short* WB = (short*)(ws + 256 + 16777216);   // weight bf16 scratch 32 MB; becomes AO
    short* AO = WB;                              // attn out [4096][4096] bf16
    short* WOB = (short*)(ws + 256 + 16777216 + 33554432);  // wo bf16 (only if ws allows)
    short* Qb = (short*)d_out;                   // Q bf16, d_out lower half [0,32MB)
    short* Xb = (short*)d_out + 16777216;        // x bf16, d_out upper half (dead after KV gemm)
    short* Vtb = (short*)d_out + 16777216;       // V^T [4096 dh][1024 tok] = 8 MB (reuses Xb)
    float2* cs = (float2*)((char*)d_out + 33554432 + 8388608);  // rope LUT 512 KB (after Vt)
    const bool big_ws = ws_size >= (size_t)(256 + 16777216 + 33554432 + 33554432);

    detect_dtype<<<1, 256, 0, stream>>>((const unsigned int*)x, 0, flag);
    detect_dtype<<<1, 256, 0, stream>>>((const unsigned int*)freqs, 100, flag + 1);
    to_bf16<<<8192, 256, 0, stream>>>(x, Xb, flag, 2097152);
    to_bf16<<<8192, 256, 0, stream>>>(wq, WB, flag, 2097152);
    gemm256<<<dim3(16, 16), 512, 0, stream>>>(Xb, WB, Qb, 4096, 4096, 4096, flag, 0);
    to_bf16<<<2048, 256, 0, stream>>>(wk, WB, flag, 524288);
    to_bf16<<<2048, 256, 0, stream>>>(wv, WB + 4194304, flag, 524288);
    gemm256<<<dim3(8, 16), 512, 0, stream>>>(Xb, WB, KV, 4096, 2048, 4096, flag, 0);
    // Xb dead from here: its region becomes V^T + rope LUT
    transpose_v<<<dim3(16, 8, 4), 256, 0, stream>>>(KV, Vtb);
    rope_lut<<<256, 256, 0, stream>>>(freqs, flag + 1, cs);
    rope_kernel<<<10240, 256, 0, stream>>>(Qb, KV, cs);
    attn_kernel<<<dim3(16, 32, 4), 256, 0, stream>>>(Qb, KV, Vtb, AO);
    if (big_ws) {
        to_bf16<<<8192, 256, 0, stream>>>(wo, WOB, flag, 2097152);
        gemm256<<<dim3(16, 16), 512, 0, stream>>>(AO, WOB, d_out, 4096, 4096, 4096, flag, 1);
    } else {
        gemm_bt_f<<<dim3(32, 32), 256, 0, stream>>>(AO, wo, d_out, 4096, 4096, 4096, flag, 1, 1);
    }
}